// Round 4
// baseline (125.166 us; speedup 1.0000x reference)
//
#include <hip/hip_runtime.h>
#include <hip/hip_bf16.h>
#include <cstddef>

#define BB 4
#define CC 64
#define UU 5
#define VV 5
#define HH 64
#define WW 64
#define NIJ (69*69)   // 4761

__device__ __forceinline__ float rdlane(float v, int l) {
    return __uint_as_float((unsigned)__builtin_amdgcn_readlane((int)__float_as_uint(v), l));
}

// ---------------------------------------------------------------------------
// K1: one pass over x -> 4 means, channel-first coalesced outputs.
// 256 blocks x 512 threads, 2-stage u-pipeline (prefetch u+1 while doing u).
// ---------------------------------------------------------------------------
#define K1_PREF(Ax, Bx, uu)                                            \
    { const float4* xt = xb4 + (size_t)(uu) * 5120;                    \
      _Pragma("unroll")                                                \
      for (int v = 0; v < 5; ++v) {                                    \
          Ax[v] = xt[v*1024 + t];                                      \
          Bx[v] = xt[v*1024 + 512 + t];                                \
      } }

#define K1_PROC(Ax, Bx, uu)                                            \
    { float uh0 = 0.f, uh1 = 0.f;                                      \
      _Pragma("unroll")                                                \
      for (int v = 0; v < 5; ++v) {                                    \
          float4 a = Ax[v], b = Bx[v];                                 \
          hw0.x += a.x; hw0.y += a.y; hw0.z += a.z; hw0.w += a.w;      \
          hw1.x += b.x; hw1.y += b.y; hw1.z += b.z; hw1.w += b.w;      \
          float r0 = (a.x + a.y) + (a.z + a.w);                        \
          float r1 = (b.x + b.y) + (b.z + b.w);                        \
          r0 += __shfl_xor(r0, 1); r0 += __shfl_xor(r0, 2);            \
          r0 += __shfl_xor(r0, 4); r0 += __shfl_xor(r0, 8);            \
          r1 += __shfl_xor(r1, 1); r1 += __shfl_xor(r1, 2);            \
          r1 += __shfl_xor(r1, 4); r1 += __shfl_xor(r1, 8);            \
          uh0 += r0; uh1 += r1;                                        \
          float4 cs;                                                   \
          cs.x = a.x + b.x; cs.y = a.y + b.y;                          \
          cs.z = a.z + b.z; cs.w = a.w + b.w;                          \
          cs.x += __shfl_xor(cs.x, 16); cs.y += __shfl_xor(cs.y, 16);  \
          cs.z += __shfl_xor(cs.z, 16); cs.w += __shfl_xor(cs.w, 16);  \
          cs.x += __shfl_xor(cs.x, 32); cs.y += __shfl_xor(cs.y, 32);  \
          cs.z += __shfl_xor(cs.z, 32); cs.w += __shfl_xor(cs.w, 32);  \
          vwacc[v].x += cs.x; vwacc[v].y += cs.y;                      \
          vwacc[v].z += cs.z; vwacc[v].w += cs.w;                      \
          float s = (cs.x + cs.y) + (cs.z + cs.w);                     \
          s += __shfl_xor(s, 1); s += __shfl_xor(s, 2);                \
          s += __shfl_xor(s, 4); s += __shfl_xor(s, 8);                \
          if (lane == 0) uv_lds[wave][(uu)*5 + v] = s;                 \
      }                                                                \
      if ((t & 15) == 0) {                                             \
          const int hb = t >> 4;                                       \
          m_uh[(size_t)bc*320 + (uu)*64 + hb]      = uh0 * (1.f/320.f);\
          m_uh[(size_t)bc*320 + (uu)*64 + 32 + hb] = uh1 * (1.f/320.f);\
      } }

__global__ __launch_bounds__(512) void k1_means(const float* __restrict__ x,
        float* __restrict__ m_hw, float* __restrict__ m_uh,
        float* __restrict__ m_vw, float* __restrict__ m_uv) {
    const int bc = blockIdx.x;
    const float4* xb4 = (const float4*)(x + (size_t)bc * (UU*VV*HH*WW));
    const int t    = threadIdx.x;     // 0..511
    const int wave = t >> 6;
    const int lane = t & 63;

    __shared__ float4 vw_lds[8][5][16];
    __shared__ float  uv_lds[8][25];

    float4 hw0 = make_float4(0.f,0.f,0.f,0.f);
    float4 hw1 = make_float4(0.f,0.f,0.f,0.f);
    float4 vwacc[5];
    #pragma unroll
    for (int v = 0; v < 5; ++v) vwacc[v] = make_float4(0.f,0.f,0.f,0.f);

    float4 A0[5], B0[5], A1[5], B1[5];
    K1_PREF(A0, B0, 0)
    K1_PREF(A1, B1, 1) K1_PROC(A0, B0, 0)
    K1_PREF(A0, B0, 2) K1_PROC(A1, B1, 1)
    K1_PREF(A1, B1, 3) K1_PROC(A0, B0, 2)
    K1_PREF(A0, B0, 4) K1_PROC(A1, B1, 3)
    K1_PROC(A0, B0, 4)

    #pragma unroll
    for (int v = 0; v < 5; ++v)
        if (lane < 16) vw_lds[wave][v][lane] = vwacc[v];
    __syncthreads();

    float4* mh4 = (float4*)m_hw + (size_t)bc * 1024;
    const float s25 = 1.f/25.f;
    float4 o0, o1;
    o0.x = hw0.x*s25; o0.y = hw0.y*s25; o0.z = hw0.z*s25; o0.w = hw0.w*s25;
    o1.x = hw1.x*s25; o1.y = hw1.y*s25; o1.z = hw1.z*s25; o1.w = hw1.w*s25;
    mh4[t] = o0;
    mh4[512 + t] = o1;

    if (t < 80) {
        const int v = t >> 4, wq = t & 15;
        float4 s = vw_lds[0][v][wq];
        #pragma unroll
        for (int w8 = 1; w8 < 8; ++w8) {
            float4 p = vw_lds[w8][v][wq];
            s.x += p.x; s.y += p.y; s.z += p.z; s.w += p.w;
        }
        const float sc = 1.f/320.f;
        s.x *= sc; s.y *= sc; s.z *= sc; s.w *= sc;
        ((float4*)m_vw)[(size_t)bc*80 + t] = s;
    }
    if (t < 25) {
        float s = 0.f;
        #pragma unroll
        for (int w8 = 0; w8 < 8; ++w8) s += uv_lds[w8][t];
        m_uv[(size_t)bc*25 + t] = s * (1.f/4096.f);
    }
}

// ---------------------------------------------------------------------------
// K1b: transpose channel-first means -> channel-last grid_t[b][ij][c]
// ---------------------------------------------------------------------------
__global__ __launch_bounds__(256) void k1b_assemble(
        const float* __restrict__ m_hw, const float* __restrict__ m_uh,
        const float* __restrict__ m_vw, const float* __restrict__ m_uv,
        float* __restrict__ grid_t) {
    __shared__ float tile[64][68];
    const int t = threadIdx.x;
    const int c = t >> 2, qsel = t & 3;
    const int blk = blockIdx.x;
    const bool top = blk < 256;
    const int b = top ? (blk >> 6) : (blk - 256) / 5;
    const int r = top ? (blk & 63) : (blk - 256) % 5;   // h (top) or v (bot)

    const float4* src4 = top
        ? (const float4*)m_hw + ((size_t)(b*64 + c) * 1024 + r*16)
        : (const float4*)m_vw + ((size_t)(b*64 + c) * 80  + r*16);
    #pragma unroll
    for (int j = 0; j < 4; ++j) {
        float4 v = src4[4*j + qsel];
        const int w = (4*j + qsel) * 4;
        tile[w+0][c] = v.x; tile[w+1][c] = v.y;
        tile[w+2][c] = v.z; tile[w+3][c] = v.w;
    }
    __syncthreads();

    const int i = top ? r : (64 + r);
    float4* dst4 = (float4*)grid_t + ((size_t)b*NIJ + i*69) * 16;
    #pragma unroll
    for (int k = 0; k < 4; ++k) {
        const int oidx = k*256 + t;
        const int w = oidx >> 4, cq = (oidx & 15) * 4;
        float4 v;
        v.x = tile[w][cq]; v.y = tile[w][cq+1];
        v.z = tile[w][cq+2]; v.w = tile[w][cq+3];
        dst4[oidx] = v;
    }
    for (int idx = t; idx < 320; idx += 256) {
        const int u = idx >> 6, cc = idx & 63;
        float val = top ? m_uh[(size_t)(b*64 + cc)*320 + u*64 + r]
                        : m_uv[(size_t)(b*64 + cc)*25  + u*5  + r];
        grid_t[((size_t)b*NIJ + i*69 + 64 + u)*64 + cc] = val;
    }
}

// ---------------------------------------------------------------------------
// K2: per-position MLP + region conv. 256 threads = 4 waves x 18 columns.
// __launch_bounds__(256, 1): weight arrays must stay in VGPRs (R2 lesson).
// ---------------------------------------------------------------------------
#define LOADROW(dst, src)                                              \
    { _Pragma("unroll")                                                \
      for (int q = 0; q < 16; ++q) {                                   \
          float4 t4 = ((const float4*)(src))[lane*16 + q];             \
          dst[4*q+0] = t4.x; dst[4*q+1] = t4.y;                        \
          dst[4*q+2] = t4.z; dst[4*q+3] = t4.w;                        \
      } }

#define DOT64(res, wr, src)                                            \
    float res;                                                         \
    { float _a0=0.f,_a1=0.f,_a2=0.f,_a3=0.f;                           \
      _Pragma("unroll")                                                \
      for (int cc2 = 0; cc2 < 64; cc2 += 4) {                          \
          _a0 = fmaf(wr[cc2+0], rdlane(src, cc2+0), _a0);              \
          _a1 = fmaf(wr[cc2+1], rdlane(src, cc2+1), _a1);              \
          _a2 = fmaf(wr[cc2+2], rdlane(src, cc2+2), _a2);              \
          _a3 = fmaf(wr[cc2+3], rdlane(src, cc2+3), _a3);              \
      }                                                                \
      res = (_a0 + _a1) + (_a2 + _a3); }

#define MLP_BODY(J)                                                    \
    {                                                                  \
        const int jj = (J);                                            \
        float v = gtb[(size_t)(i*69 + jj) * CC + lane];                \
        DOT64(d1, w1r, v);                                             \
        float acc1 = d1 + b1v;                                         \
        float ya = acc1 / (1.f + __expf(-acc1));                       \
        DOT64(d2, w2r, ya);                                            \
        float acc2 = d2 + b2v;                                         \
        DOT64(d3, fr, acc2);                                           \
        sp[(size_t)(jj - jbase) * sstr] = d3 + fbv;                    \
    }

__global__ __launch_bounds__(256, 1) void k2_mlp(
        const float* __restrict__ grid_t,
        const float* __restrict__ w1, const float* __restrict__ b1,
        const float* __restrict__ w2, const float* __restrict__ b2,
        const float* __restrict__ fw0, const float* __restrict__ fb0,
        const float* __restrict__ fw1, const float* __restrict__ fb1,
        const float* __restrict__ fw2, const float* __restrict__ fb2,
        const float* __restrict__ fw3, const float* __restrict__ fb3,
        float* __restrict__ mod_hw, float* __restrict__ mod_uh,
        float* __restrict__ mod_vw, float* __restrict__ mod_uv) {
    const int row  = blockIdx.x;          // 0..275
    const int b    = row / 69;
    const int i    = row % 69;
    const int wave = threadIdx.x >> 6;
    const int lane = threadIdx.x & 63;

    const int j0 = wave * 18;
    const int j1 = min(69, j0 + 18);
    const bool top = (i < 64);

    const float* fwA = top ? fw0 : fw3;
    const float* fbA = top ? fb0 : fb3;
    const float* fwB = top ? fw2 : fw1;
    const float* fbB = top ? fb2 : fb1;

    float w1r[64], w2r[64], fr[64];
    LOADROW(w1r, w1);
    LOADROW(w2r, w2);
    const float b1v = b1[lane];
    const float b2v = b2[lane];

    const float* gtb = grid_t + (size_t)b * NIJ * CC;
    const int cbl = b * CC + lane;

    const int jm = min(j1, 64);
    if (j0 < jm) {                        // region A: j < 64
        LOADROW(fr, fwA);
        const float fbv = fbA[lane];
        float* sp; int sstr; const int jbase = 0;
        if (top) { sp = mod_hw + ((size_t)cbl*64 + i)*64;          sstr = 1; }
        else     { sp = mod_vw + (size_t)cbl*320 + (i-64)*64;      sstr = 1; }
        for (int j = j0; j < jm; ++j) MLP_BODY(j)
    }
    if (j1 > 64) {                        // region B: j >= 64
        LOADROW(fr, fwB);
        const float fbv = fbB[lane];
        float* sp; int sstr; const int jbase = 64;
        if (top) { sp = mod_uh + (size_t)cbl*320 + i;              sstr = 64; }
        else     { sp = mod_uv + (size_t)cbl*25 + (i-64);          sstr = 5;  }
        const int jb = max(j0, 64);
        for (int j = jb; j < j1; ++j) MLP_BODY(j)
    }
}

// ---------------------------------------------------------------------------
// K3: out = x * (mod_hw + mod_uv + mod_uh + mod_vw)
// 512 blocks = (bc, h-half), 512 threads. No LDS, no barrier; all modifiers
// register/SGPR-resident; 25-tile fully-static unrolled stream.
// ---------------------------------------------------------------------------
__global__ __launch_bounds__(512) void k3_apply(
        const float* __restrict__ x,
        const float* __restrict__ mod_hw, const float* __restrict__ mod_uh,
        const float* __restrict__ mod_vw, const float* __restrict__ mod_uv,
        float* __restrict__ out) {
    const int blk  = blockIdx.x;          // bc*2 + half
    const int bc   = blk >> 1;
    const int half = blk & 1;
    const int t    = threadIdx.x;         // 0..511
    const int base = half*512 + t;        // quad index in tile, 0..1023
    const int h    = base >> 4;           // 0..63

    float4 mh = ((const float4*)(mod_hw + (size_t)bc * 4096))[base];
    float uh[5];
    #pragma unroll
    for (int u = 0; u < 5; ++u) uh[u] = mod_uh[(size_t)bc*320 + u*64 + h];
    float4 vw[5];
    #pragma unroll
    for (int v = 0; v < 5; ++v)
        vw[v] = ((const float4*)(mod_vw + (size_t)bc*320 + v*64))[t & 15];
    float uv[25];
    #pragma unroll
    for (int k = 0; k < 25; ++k) uv[k] = mod_uv[(size_t)bc*25 + k];  // uniform

    const float4* x4 = (const float4*)(x + (size_t)bc * (UU*VV*HH*WW));
    float4* o4 = (float4*)(out + (size_t)bc * (UU*VV*HH*WW));

    #pragma unroll
    for (int u = 0; u < 5; ++u) {
        #pragma unroll
        for (int v = 0; v < 5; ++v) {
            const int idx = (u*5 + v)*1024 + base;
            float4 xv = x4[idx];
            const float s = uh[u] + uv[u*5 + v];
            float4 r;
            r.x = xv.x * (mh.x + vw[v].x + s);
            r.y = xv.y * (mh.y + vw[v].y + s);
            r.z = xv.z * (mh.z + vw[v].z + s);
            r.w = xv.w * (mh.w + vw[v].w + s);
            o4[idx] = r;
        }
    }
}

// ---------------------------------------------------------------------------
extern "C" void kernel_launch(void* const* d_in, const int* in_sizes, int n_in,
                              void* d_out, int out_size, void* d_ws, size_t ws_size,
                              hipStream_t stream) {
    const float* x   = (const float*)d_in[0];
    const float* w1  = (const float*)d_in[1];
    const float* b1  = (const float*)d_in[2];
    const float* w2  = (const float*)d_in[3];
    const float* b2  = (const float*)d_in[4];
    const float* fw0 = (const float*)d_in[5];
    const float* fb0 = (const float*)d_in[6];
    const float* fw1 = (const float*)d_in[7];
    const float* fb1 = (const float*)d_in[8];
    const float* fw2 = (const float*)d_in[9];
    const float* fb2 = (const float*)d_in[10];
    const float* fw3 = (const float*)d_in[11];
    const float* fb3 = (const float*)d_in[12];

    float* ws = (float*)d_ws;
    float* grid_t = ws;                        // 4*4761*64      = 1,218,816
    float* m_hw   = ws + 1218816;              // 256*4096       = 1,048,576
    float* m_uh   = m_hw + 1048576;            // 256*320        =    81,920
    float* m_vw   = m_uh + 81920;              // 256*320        =    81,920
    float* m_uv   = m_vw + 81920;              // 256*25         =     6,400
    float* mod_hw = m_hw;
    float* mod_uh = m_uh;
    float* mod_vw = m_vw;
    float* mod_uv = m_uv;

    k1_means<<<BB*CC, 512, 0, stream>>>(x, m_hw, m_uh, m_vw, m_uv);
    k1b_assemble<<<BB*CC + BB*VV, 256, 0, stream>>>(m_hw, m_uh, m_vw, m_uv, grid_t);
    k2_mlp<<<BB*69, 256, 0, stream>>>(grid_t, w1, b1, w2, b2,
                                      fw0, fb0, fw1, fb1, fw2, fb2, fw3, fb3,
                                      mod_hw, mod_uh, mod_vw, mod_uv);
    k3_apply<<<BB*CC*2, 512, 0, stream>>>(x, mod_hw, mod_uh, mod_vw, mod_uv,
                                          (float*)d_out);
}

// Round 5
// 113.411 us; speedup vs baseline: 1.1036x; 1.1036x over previous
//
#include <hip/hip_runtime.h>
#include <hip/hip_bf16.h>
#include <cstddef>

#define BB 4
#define CC 64
#define UU 5
#define VV 5
#define HH 64
#define WW 64
#define NIJ (69*69)   // 4761

__device__ __forceinline__ float rdlane(float v, int l) {
    return __uint_as_float((unsigned)__builtin_amdgcn_readlane((int)__float_as_uint(v), l));
}

// ---------------------------------------------------------------------------
// K1: grid = B*C*U = 1280 blocks, 512 threads. Block (bc,u) reads its 5 tiles
// in one burst (10 float4 loads/thread, ~64 VGPR, no spill), computes:
//   part_hw[blk][1024 f4]  (unscaled, summed over v; k1b sums over u, /25)
//   part_vw[blk][v][w]     (unscaled col sums; k1b sums over u, /320)
//   part_uv[bc][u][v]      (final, /4096)
//   m_uh[bc][u][h]         (final, /320)
// part_* live in d_out (scratch until k3 rewrites it).
// ---------------------------------------------------------------------------
__global__ __launch_bounds__(512) void k1_means(const float* __restrict__ x,
        float* __restrict__ part_hw, float* __restrict__ part_vw,
        float* __restrict__ part_uv, float* __restrict__ m_uh) {
    const int blk = blockIdx.x;       // bc*5 + u
    const int bc  = blk / 5;
    const int u   = blk % 5;
    const float4* xt = (const float4*)x + (size_t)bc * 25600 + (size_t)u * 5120;
    const int t    = threadIdx.x;     // 0..511
    const int wave = t >> 6;
    const int lane = t & 63;

    __shared__ float4 vw_lds[8][5][16];
    __shared__ float  uv_lds[8][5];

    float4 A[5], B[5];
    #pragma unroll
    for (int v = 0; v < 5; ++v) {
        A[v] = xt[v*1024 + t];
        B[v] = xt[v*1024 + 512 + t];
    }

    float4 hw0 = make_float4(0.f,0.f,0.f,0.f);
    float4 hw1 = make_float4(0.f,0.f,0.f,0.f);
    float uh0 = 0.f, uh1 = 0.f;

    #pragma unroll
    for (int v = 0; v < 5; ++v) {
        float4 a = A[v], b = B[v];
        hw0.x += a.x; hw0.y += a.y; hw0.z += a.z; hw0.w += a.w;
        hw1.x += b.x; hw1.y += b.y; hw1.z += b.z; hw1.w += b.w;
        // row sums over w (16 lanes per h-row)
        float r0 = (a.x + a.y) + (a.z + a.w);
        float r1 = (b.x + b.y) + (b.z + b.w);
        r0 += __shfl_xor(r0, 1); r0 += __shfl_xor(r0, 2);
        r0 += __shfl_xor(r0, 4); r0 += __shfl_xor(r0, 8);
        r1 += __shfl_xor(r1, 1); r1 += __shfl_xor(r1, 2);
        r1 += __shfl_xor(r1, 4); r1 += __shfl_xor(r1, 8);
        uh0 += r0; uh1 += r1;
        // column partial over this wave's 8 h-rows
        float4 cs;
        cs.x = a.x + b.x; cs.y = a.y + b.y; cs.z = a.z + b.z; cs.w = a.w + b.w;
        cs.x += __shfl_xor(cs.x, 16); cs.y += __shfl_xor(cs.y, 16);
        cs.z += __shfl_xor(cs.z, 16); cs.w += __shfl_xor(cs.w, 16);
        cs.x += __shfl_xor(cs.x, 32); cs.y += __shfl_xor(cs.y, 32);
        cs.z += __shfl_xor(cs.z, 32); cs.w += __shfl_xor(cs.w, 32);
        if (lane < 16) vw_lds[wave][v][lane] = cs;
        // tile total (this wave's share)
        float s = (cs.x + cs.y) + (cs.z + cs.w);
        s += __shfl_xor(s, 1); s += __shfl_xor(s, 2);
        s += __shfl_xor(s, 4); s += __shfl_xor(s, 8);
        if (lane == 0) uv_lds[wave][v] = s;
    }

    // uh final for (bc,u)
    if ((t & 15) == 0) {
        const int hb = t >> 4;    // 0..31
        m_uh[(size_t)bc*320 + u*64 + hb]      = uh0 * (1.f/320.f);
        m_uh[(size_t)bc*320 + u*64 + 32 + hb] = uh1 * (1.f/320.f);
    }
    // hw partial (unscaled), contiguous 16KB
    float4* ph4 = (float4*)part_hw + (size_t)blk * 1024;
    ph4[t]       = hw0;
    ph4[512 + t] = hw1;

    __syncthreads();

    if (t < 80) {   // vw partial: cross-wave reduce, unscaled
        const int v = t >> 4, wq = t & 15;
        float4 s = vw_lds[0][v][wq];
        #pragma unroll
        for (int w8 = 1; w8 < 8; ++w8) {
            float4 p = vw_lds[w8][v][wq];
            s.x += p.x; s.y += p.y; s.z += p.z; s.w += p.w;
        }
        ((float4*)part_vw)[(size_t)blk*80 + v*16 + wq] = s;
    }
    if (t < 5) {    // uv final
        float s = 0.f;
        #pragma unroll
        for (int w8 = 0; w8 < 8; ++w8) s += uv_lds[w8][t];
        part_uv[(size_t)bc*25 + u*5 + t] = s * (1.f/4096.f);
    }
}

// ---------------------------------------------------------------------------
// K1b: sum u-partials, transpose c -> channel-last grid_t[b][ij][c]
// blocks 0..255: (b,h) top rows; 256..275: (b,v) bottom rows. 256 thr.
// ---------------------------------------------------------------------------
__global__ __launch_bounds__(256) void k1b_assemble(
        const float* __restrict__ part_hw, const float* __restrict__ part_vw,
        const float* __restrict__ part_uv, const float* __restrict__ m_uh,
        float* __restrict__ grid_t) {
    __shared__ float tile[64][68];
    const int t = threadIdx.x;
    const int c = t >> 2, qsel = t & 3;
    const int blk = blockIdx.x;
    const bool top = blk < 256;
    const int b = top ? (blk >> 6) : (blk - 256) / 5;
    const int r = top ? (blk & 63) : (blk - 256) % 5;   // h (top) or v (bot)

    const float sc = top ? (1.f/25.f) : (1.f/320.f);
    #pragma unroll
    for (int j = 0; j < 4; ++j) {
        float4 acc = make_float4(0.f,0.f,0.f,0.f);
        #pragma unroll
        for (int u = 0; u < 5; ++u) {
            float4 v = top
                ? ((const float4*)part_hw)[((size_t)(b*64 + c)*5 + u)*1024 + r*16 + 4*j + qsel]
                : ((const float4*)part_vw)[((size_t)(b*64 + c)*5 + u)*80   + r*16 + 4*j + qsel];
            acc.x += v.x; acc.y += v.y; acc.z += v.z; acc.w += v.w;
        }
        const int w = (4*j + qsel) * 4;
        tile[w+0][c] = acc.x * sc; tile[w+1][c] = acc.y * sc;
        tile[w+2][c] = acc.z * sc; tile[w+3][c] = acc.w * sc;
    }
    __syncthreads();

    const int i = top ? r : (64 + r);
    float4* dst4 = (float4*)grid_t + ((size_t)b*NIJ + i*69) * 16;
    #pragma unroll
    for (int k = 0; k < 4; ++k) {
        const int oidx = k*256 + t;
        const int w = oidx >> 4, cq = (oidx & 15) * 4;
        float4 v;
        v.x = tile[w][cq]; v.y = tile[w][cq+1];
        v.z = tile[w][cq+2]; v.w = tile[w][cq+3];
        dst4[oidx] = v;
    }
    for (int idx = t; idx < 320; idx += 256) {
        const int u = idx >> 6, cc = idx & 63;
        float val = top ? m_uh[(size_t)(b*64 + cc)*320 + u*64 + r]
                        : part_uv[(size_t)(b*64 + cc)*25  + u*5  + r];
        grid_t[((size_t)b*NIJ + i*69 + 64 + u)*64 + cc] = val;
    }
}

// ---------------------------------------------------------------------------
// K2: per-position MLP + region conv. 256 threads = 4 waves x 18 columns.
// __launch_bounds__(256, 1): weight arrays must stay in VGPRs (R2 lesson).
// ---------------------------------------------------------------------------
#define LOADROW(dst, src)                                              \
    { _Pragma("unroll")                                                \
      for (int q = 0; q < 16; ++q) {                                   \
          float4 t4 = ((const float4*)(src))[lane*16 + q];             \
          dst[4*q+0] = t4.x; dst[4*q+1] = t4.y;                        \
          dst[4*q+2] = t4.z; dst[4*q+3] = t4.w;                        \
      } }

#define DOT64(res, wr, src)                                            \
    float res;                                                         \
    { float _a0=0.f,_a1=0.f,_a2=0.f,_a3=0.f;                           \
      _Pragma("unroll")                                                \
      for (int cc2 = 0; cc2 < 64; cc2 += 4) {                          \
          _a0 = fmaf(wr[cc2+0], rdlane(src, cc2+0), _a0);              \
          _a1 = fmaf(wr[cc2+1], rdlane(src, cc2+1), _a1);              \
          _a2 = fmaf(wr[cc2+2], rdlane(src, cc2+2), _a2);              \
          _a3 = fmaf(wr[cc2+3], rdlane(src, cc2+3), _a3);              \
      }                                                                \
      res = (_a0 + _a1) + (_a2 + _a3); }

#define MLP_BODY(J)                                                    \
    {                                                                  \
        const int jj = (J);                                            \
        float v = gtb[(size_t)(i*69 + jj) * CC + lane];                \
        DOT64(d1, w1r, v);                                             \
        float acc1 = d1 + b1v;                                         \
        float ya = acc1 / (1.f + __expf(-acc1));                       \
        DOT64(d2, w2r, ya);                                            \
        float acc2 = d2 + b2v;                                         \
        DOT64(d3, fr, acc2);                                           \
        sp[(size_t)(jj - jbase) * sstr] = d3 + fbv;                    \
    }

__global__ __launch_bounds__(256, 1) void k2_mlp(
        const float* __restrict__ grid_t,
        const float* __restrict__ w1, const float* __restrict__ b1,
        const float* __restrict__ w2, const float* __restrict__ b2,
        const float* __restrict__ fw0, const float* __restrict__ fb0,
        const float* __restrict__ fw1, const float* __restrict__ fb1,
        const float* __restrict__ fw2, const float* __restrict__ fb2,
        const float* __restrict__ fw3, const float* __restrict__ fb3,
        float* __restrict__ mod_hw, float* __restrict__ mod_uh,
        float* __restrict__ mod_vw, float* __restrict__ mod_uv) {
    const int row  = blockIdx.x;          // 0..275
    const int b    = row / 69;
    const int i    = row % 69;
    const int wave = threadIdx.x >> 6;
    const int lane = threadIdx.x & 63;

    const int j0 = wave * 18;
    const int j1 = min(69, j0 + 18);
    const bool top = (i < 64);

    const float* fwA = top ? fw0 : fw3;
    const float* fbA = top ? fb0 : fb3;
    const float* fwB = top ? fw2 : fw1;
    const float* fbB = top ? fb2 : fb1;

    float w1r[64], w2r[64], fr[64];
    LOADROW(w1r, w1);
    LOADROW(w2r, w2);
    const float b1v = b1[lane];
    const float b2v = b2[lane];

    const float* gtb = grid_t + (size_t)b * NIJ * CC;
    const int cbl = b * CC + lane;

    const int jm = min(j1, 64);
    if (j0 < jm) {                        // region A: j < 64
        LOADROW(fr, fwA);
        const float fbv = fbA[lane];
        float* sp; int sstr; const int jbase = 0;
        if (top) { sp = mod_hw + ((size_t)cbl*64 + i)*64;          sstr = 1; }
        else     { sp = mod_vw + (size_t)cbl*320 + (i-64)*64;      sstr = 1; }
        for (int j = j0; j < jm; ++j) MLP_BODY(j)
    }
    if (j1 > 64) {                        // region B: j >= 64
        LOADROW(fr, fwB);
        const float fbv = fbB[lane];
        float* sp; int sstr; const int jbase = 64;
        if (top) { sp = mod_uh + (size_t)cbl*320 + i;              sstr = 64; }
        else     { sp = mod_uv + (size_t)cbl*25 + (i-64);          sstr = 5;  }
        const int jb = max(j0, 64);
        for (int j = jb; j < j1; ++j) MLP_BODY(j)
    }
}

// ---------------------------------------------------------------------------
// K3: out = x * (mod_hw + mod_uv + mod_uh + mod_vw)
// 512 blocks = (bc, h-half), 512 threads. No LDS, no barrier.
// ---------------------------------------------------------------------------
__global__ __launch_bounds__(512) void k3_apply(
        const float* __restrict__ x,
        const float* __restrict__ mod_hw, const float* __restrict__ mod_uh,
        const float* __restrict__ mod_vw, const float* __restrict__ mod_uv,
        float* __restrict__ out) {
    const int blk  = blockIdx.x;          // bc*2 + half
    const int bc   = blk >> 1;
    const int half = blk & 1;
    const int t    = threadIdx.x;         // 0..511
    const int base = half*512 + t;        // quad index in tile, 0..1023
    const int h    = base >> 4;           // 0..63

    float4 mh = ((const float4*)(mod_hw + (size_t)bc * 4096))[base];
    float uh[5];
    #pragma unroll
    for (int u = 0; u < 5; ++u) uh[u] = mod_uh[(size_t)bc*320 + u*64 + h];
    float4 vw[5];
    #pragma unroll
    for (int v = 0; v < 5; ++v)
        vw[v] = ((const float4*)(mod_vw + (size_t)bc*320 + v*64))[t & 15];
    float uv[25];
    #pragma unroll
    for (int k = 0; k < 25; ++k) uv[k] = mod_uv[(size_t)bc*25 + k];  // uniform

    const float4* x4 = (const float4*)(x + (size_t)bc * (UU*VV*HH*WW));
    float4* o4 = (float4*)(out + (size_t)bc * (UU*VV*HH*WW));

    #pragma unroll
    for (int u = 0; u < 5; ++u) {
        #pragma unroll
        for (int v = 0; v < 5; ++v) {
            const int idx = (u*5 + v)*1024 + base;
            float4 xv = x4[idx];
            const float s = uh[u] + uv[u*5 + v];
            float4 r;
            r.x = xv.x * (mh.x + vw[v].x + s);
            r.y = xv.y * (mh.y + vw[v].y + s);
            r.z = xv.z * (mh.z + vw[v].z + s);
            r.w = xv.w * (mh.w + vw[v].w + s);
            o4[idx] = r;
        }
    }
}

// ---------------------------------------------------------------------------
extern "C" void kernel_launch(void* const* d_in, const int* in_sizes, int n_in,
                              void* d_out, int out_size, void* d_ws, size_t ws_size,
                              hipStream_t stream) {
    const float* x   = (const float*)d_in[0];
    const float* w1  = (const float*)d_in[1];
    const float* b1  = (const float*)d_in[2];
    const float* w2  = (const float*)d_in[3];
    const float* b2  = (const float*)d_in[4];
    const float* fw0 = (const float*)d_in[5];
    const float* fb0 = (const float*)d_in[6];
    const float* fw1 = (const float*)d_in[7];
    const float* fb1 = (const float*)d_in[8];
    const float* fw2 = (const float*)d_in[9];
    const float* fb2 = (const float*)d_in[10];
    const float* fw3 = (const float*)d_in[11];
    const float* fb3 = (const float*)d_in[12];

    float* ws = (float*)d_ws;
    float* grid_t = ws;                        // 4*4761*64      = 1,218,816
    float* mod_hw = ws + 1218816;              // 256*4096       = 1,048,576
    float* mod_uh = mod_hw + 1048576;          // 256*320        =    81,920
    float* mod_vw = mod_uh + 81920;            // 256*320        =    81,920
    float* mod_uv = mod_vw + 81920;            // 256*25         =     6,400

    // d_out doubles as scratch for k1 partials (k3 fully rewrites it).
    float* part_hw = (float*)d_out;            // 1280*4096      = 5,242,880
    float* part_vw = part_hw + 5242880;        // 1280*320       =   409,600
    float* part_uv = part_vw + 409600;         // 256*25         =     6,400
    float* m_uh    = mod_uh;                   // k1 means; overwritten by k2 later

    k1_means<<<BB*CC*UU, 512, 0, stream>>>(x, part_hw, part_vw, part_uv, m_uh);
    k1b_assemble<<<BB*CC + BB*VV, 256, 0, stream>>>(part_hw, part_vw, part_uv, m_uh, grid_t);
    k2_mlp<<<BB*69, 256, 0, stream>>>(grid_t, w1, b1, w2, b2,
                                      fw0, fb0, fw1, fb1, fw2, fb2, fw3, fb3,
                                      mod_hw, mod_uh, mod_vw, mod_uv);
    k3_apply<<<BB*CC*2, 512, 0, stream>>>(x, mod_hw, mod_uh, mod_vw, mod_uv,
                                          (float*)d_out);
}